// Round 2
// baseline (2623.747 us; speedup 1.0000x reference)
//
#include <hip/hip_runtime.h>
#include <hip/hip_bf16.h>
#include <math.h>

// ---------------- problem constants ----------------
#define N_BATCH 2
#define HH 50
#define WW 84
#define NPIX (HH*WW)           // 4200
#define KA (NPIX*9)            // 37800
#define N_PRE 6000
#define N_POST 300
#define NMS_T 0.7f
#define NEGV (-1e9f)
#define NWORDS 94              // ceil(6000/64)

// d_out offsets (floats)
#define OFF_LOCS   0
#define OFF_SCORES (N_BATCH*KA*4)                  // 302400
#define OFF_ROIS   (OFF_SCORES + N_BATCH*KA*2)     // 453600
#define OFF_RIDX   (OFF_ROIS + N_BATCH*N_POST*4)   // 456000
#define OFF_ANCH   (OFF_RIDX + N_BATCH*N_POST)     // 456600

// ws offsets (bytes), all 16B aligned
#define WS_HID    0ull
#define WS_FG     17203200ull
#define WS_ROI    17505600ull
#define WS_ITEMS  18715200ull
#define WS_SITEMS 19320000ull
#define WS_SBOX   19416000ull
#define WS_MASK   19608000ull
#define WS_DIAG   28632000ull   // 2*6000*8 = 96000 B

typedef unsigned long long u64;
typedef unsigned u32;

// ---------------- anchors ----------------
__global__ void k_anchor(float* __restrict__ out) {
  int k = blockIdx.x * 256 + threadIdx.x;
  if (k >= KA) return;
  int a = k % 9; int pj = k / 9; int j = pj % WW; int i = pj / WW;
  int ri = a / 3, si = a % 3;
  double ratio = (ri == 0) ? 0.5 : ((ri == 1) ? 1.0 : 2.0);
  double scale = (si == 0) ? 8.0 : ((si == 1) ? 16.0 : 32.0);
  double h = 16.0 * scale * sqrt(ratio);
  double w = 16.0 * scale * sqrt(1.0 / ratio);
  float y1 = (float)(8.0 - h * 0.5), x1 = (float)(8.0 - w * 0.5);
  float y2 = (float)(8.0 + h * 0.5), x2 = (float)(8.0 + w * 0.5);
  float sy = (float)(i * 16), sx = (float)(j * 16);
  ((float4*)out)[OFF_ANCH / 4 + k] = make_float4(sy + y1, sx + x1, sy + y2, sx + x2);
}

// ---------------- conv1 3x3 512->512 + relu ----------------
// 64-thread block = 64 oc x 1 output row. thread = 4 oc x 21 px (84 accs).
// LDS floats/FMA = (23 x + 12 w)/252 = 0.14 -> FMA-issue-bound, not LDS-bound.
__global__ __launch_bounds__(64) void k_conv1(const float* __restrict__ x,
    const float* __restrict__ w, const float* __restrict__ bias,
    float* __restrict__ hid) {
  const int ocb = blockIdx.x;   // 0..7  (64 oc each)
  const int oh  = blockIdx.y;   // 0..49
  const int n   = blockIdx.z;   // 0..1
  const int tid = threadIdx.x;  // 0..63
  const int ocl = tid >> 2;     // 0..15
  const int g   = tid & 3;      // 0..3
  const int ow0 = g * 21;
  __shared__ float lx[8 * 3 * 88];   // 8448 B
  __shared__ float lw[64 * 73];      // [oc_local][72] pad->73, 18688 B

  float acc[4][21];
#pragma unroll
  for (int i = 0; i < 4; i++)
#pragma unroll
    for (int p = 0; p < 21; p++) acc[i][p] = 0.f;

  for (int ic0 = 0; ic0 < 512; ic0 += 8) {
    // stage x rows (col pad +-1, row-OOB -> 0): 2112 floats, 33/thread
    for (int idx = tid; idx < 8 * 3 * 88; idx += 64) {
      int ic = idx / 264; int rem = idx % 264; int ky = rem / 88; int col = rem % 88;
      int y = oh + ky - 1; int ow = col - 1;
      float v = 0.f;
      if ((unsigned)y < 50u && (unsigned)ow < 84u)
        v = x[((size_t)(n * 512 + ic0 + ic) * 50 + y) * 84 + ow];
      lx[idx] = v;
    }
    // stage weights coalesced along rr (runs of 72): 4608 floats, 72/thread
    for (int idx = tid; idx < 64 * 72; idx += 64) {
      int o = idx / 72; int rr = idx % 72;
      lw[o * 73 + rr] = w[(size_t)(ocb * 64 + o) * 4608 + ic0 * 9 + rr];
    }
    __syncthreads();
    for (int ic = 0; ic < 8; ic++) {
#pragma unroll
      for (int ky = 0; ky < 3; ky++) {
        float xv[23];
        const float* lp = &lx[(ic * 3 + ky) * 88 + ow0];
#pragma unroll
        for (int jj = 0; jj < 23; jj++) xv[jj] = lp[jj];
        const int wbase = ic * 9 + ky * 3;
#pragma unroll
        for (int kx = 0; kx < 3; kx++) {
          float wv[4];
#pragma unroll
          for (int i = 0; i < 4; i++) wv[i] = lw[(ocl * 4 + i) * 73 + wbase + kx];
#pragma unroll
          for (int i = 0; i < 4; i++)
#pragma unroll
            for (int p = 0; p < 21; p++) acc[i][p] = fmaf(wv[i], xv[p + kx], acc[i][p]);
        }
      }
    }
    __syncthreads();
  }
#pragma unroll
  for (int i = 0; i < 4; i++) {
    int oc = ocb * 64 + ocl * 4 + i;
    float bv = bias[oc];
    float* op = &hid[((size_t)(n * 512 + oc) * 50 + oh) * 84 + ow0];
#pragma unroll
    for (int p = 0; p < 21; p++) { float v = acc[i][p] + bv; op[p] = v > 0.f ? v : 0.f; }
  }
}

// ---------------- 1x1 heads (18 score + 36 loc) + fg softmax ----------------
__global__ __launch_bounds__(256) void k_head(const float* __restrict__ hid,
    const float* __restrict__ sw, const float* __restrict__ sb,
    const float* __restrict__ lww, const float* __restrict__ lb,
    float* __restrict__ out, float* __restrict__ fg) {
  const int tid = threadIdx.x;
  const int P0 = blockIdx.x * 256;
  const int P = P0 + tid;
  __shared__ float xt[32 * 256];
  __shared__ float wt[32 * 56];
  float acc[54];
#pragma unroll
  for (int o = 0; o < 54; o++) acc[o] = 0.f;

  for (int c0 = 0; c0 < 512; c0 += 32) {
    for (int i = tid; i < 32 * 256; i += 256) {
      int c = i >> 8; int lp = i & 255;
      int PP = P0 + lp;
      float v = 0.f;
      if (PP < N_BATCH * NPIX) {
        int n = PP / NPIX; int p = PP % NPIX;
        v = hid[(size_t)(n * 512 + c0 + c) * NPIX + p];
      }
      xt[c * 256 + lp] = v;
    }
    for (int i = tid; i < 32 * 54; i += 256) {
      int c = i / 54; int o = i % 54;
      wt[c * 56 + o] = (o < 18) ? sw[o * 512 + c0 + c] : lww[(o - 18) * 512 + c0 + c];
    }
    __syncthreads();
#pragma unroll 4
    for (int c = 0; c < 32; c++) {
      float xv = xt[c * 256 + tid];
      const float* wp = &wt[c * 56];
#pragma unroll
      for (int o = 0; o < 54; o++) acc[o] = fmaf(xv, wp[o], acc[o]);
    }
    __syncthreads();
  }

  if (P < N_BATCH * NPIX) {
    int n = P / NPIX; int p = P % NPIX;
    float raw[18];
#pragma unroll
    for (int o = 0; o < 18; o++) raw[o] = acc[o] + sb[o];
    size_t sbase = OFF_SCORES + ((size_t)n * KA + (size_t)p * 9) * 2;
#pragma unroll
    for (int o = 0; o < 18; o++) out[sbase + o] = raw[o];
    size_t lbase = OFF_LOCS + ((size_t)n * KA + (size_t)p * 9) * 4;
#pragma unroll
    for (int o = 0; o < 36; o++) out[lbase + o] = acc[18 + o] + lb[o];
#pragma unroll
    for (int a = 0; a < 9; a++) {
      float r0 = raw[2 * a], r1 = raw[2 * a + 1];
      float m = fmaxf(r0, r1);
      float e0 = expf(r0 - m), e1 = expf(r1 - m);
      fg[(size_t)n * KA + p * 9 + a] = e1 / (e0 + e1);
    }
  }
}

// ---------------- roi prep: loc2bbox + clip + size filter + sortable key ----------------
__global__ void k_prep(const float* __restrict__ out, const float* __restrict__ fg,
    const int* __restrict__ ihp, const int* __restrict__ iwp,
    float4* __restrict__ roi, u64* __restrict__ items) {
  int idx = blockIdx.x * 256 + threadIdx.x;
  if (idx >= N_BATCH * KA) return;
  int b = idx / KA; int k = idx % KA;
  float4 A = ((const float4*)out)[OFF_ANCH / 4 + k];
  float4 L = ((const float4*)out)[OFF_LOCS / 4 + (size_t)b * KA + k];
  float imh = (float)ihp[0], imw = (float)iwp[0];
  float h = A.z - A.x, w = A.w - A.y;
  float yc = A.x + 0.5f * h, xc = A.y + 0.5f * w;
  float cy = L.x * h + yc, cx = L.y * w + xc;
  float nh = expf(L.z) * h, nw = expf(L.w) * w;
  float y1 = cy - 0.5f * nh, x1 = cx - 0.5f * nw;
  float y2 = cy + 0.5f * nh, x2 = cx + 0.5f * nw;
  y1 = fminf(fmaxf(y1, 0.f), imh); y2 = fminf(fmaxf(y2, 0.f), imh);
  x1 = fminf(fmaxf(x1, 0.f), imw); x2 = fminf(fmaxf(x2, 0.f), imw);
  float hs = y2 - y1, wsz = x2 - x1;
  bool valid = (hs >= 16.f) && (wsz >= 16.f);
  float sc = valid ? fg[idx] : NEGV;
  u32 u = __float_as_uint(sc);
  u32 key = (u & 0x80000000u) ? ~u : (u | 0x80000000u);
  roi[(size_t)b * KA + k] = make_float4(y1, x1, y2, x2);
  items[(size_t)b * KA + k] = ((u64)key << 32) | (u32)(~(u32)k);
}

// ---------------- per-batch: radix-select top 6000 + bitonic sort ----------------
__global__ __launch_bounds__(1024) void k_select(const u64* __restrict__ items,
    const float4* __restrict__ roi, u64* __restrict__ sitems, float4* __restrict__ sbox) {
  const int b = blockIdx.x;
  const int tid = threadIdx.x;
  const int lane = tid & 63;
  const u64* it = items + (size_t)b * KA;
  __shared__ u64 arr[8192];
  __shared__ u32 hist[256];
  __shared__ u32 sh_need, sh_prefix, sh_cnt;
  if (tid == 0) { sh_need = N_PRE; sh_prefix = 0; sh_cnt = 0; }

  // 4-pass byte-wise radix select on high 32 bits (find kth=6000th largest key)
  for (int s = 3; s >= 0; s--) {
    for (int i = tid; i < 256; i += 1024) hist[i] = 0;
    __syncthreads();
    u32 prefix = sh_prefix;
    int t = 3 - s;
    for (int i = tid; i < KA; i += 1024) {
      u32 key = (u32)(it[i] >> 32);
      bool match = (t == 0) || ((key >> ((s + 1) * 8)) == prefix);
      if (match) atomicAdd(&hist[(key >> (s * 8)) & 255], 1u);
    }
    __syncthreads();
    if (tid == 0) {
      u32 need = sh_need; int chosen = 0;
      for (int bb = 255; bb >= 0; bb--) {
        if (need <= hist[bb]) { chosen = bb; break; }
        need -= hist[bb];
      }
      sh_need = need;
      sh_prefix = (prefix << 8) | (u32)chosen;
    }
    __syncthreads();
  }
  u32 kth = sh_prefix;

  // compact all items with key >= kth (wave-aggregated atomic)
  for (int i0 = 0; i0 < KA; i0 += 1024) {
    int i = i0 + tid;
    u64 v = (i < KA) ? it[i] : 0ull;
    bool sel = (i < KA) && ((u32)(v >> 32) >= kth);
    u64 bal = __ballot(sel);
    u32 cnt = (u32)__popcll(bal);
    u32 base = 0;
    if (lane == 0 && cnt) base = atomicAdd(&sh_cnt, cnt);
    base = (u32)__shfl((int)base, 0, 64);
    if (sel) {
      u32 pos = base + (u32)__popcll(bal & ((1ull << lane) - 1ull));
      if (pos < 8192) arr[pos] = v;
    }
  }
  __syncthreads();
  u32 T = sh_cnt; if (T > 8192) T = 8192;
  for (int i = (int)T + tid; i < 8192; i += 1024) arr[i] = 0ull;

  // bitonic sort, descending (key desc, then ~idx desc == idx asc)
  for (u32 k = 2; k <= 8192; k <<= 1) {
    for (u32 j = k >> 1; j > 0; j >>= 1) {
      __syncthreads();
      for (u32 i = tid; i < 8192; i += 1024) {
        u32 l = i ^ j;
        if (l > i) {
          u64 a = arr[i], c = arr[l];
          bool dir = ((i & k) == 0);
          if ((a < c) == dir) { arr[i] = c; arr[l] = a; }
        }
      }
    }
  }
  __syncthreads();
  for (int i = tid; i < N_PRE; i += 1024) {
    u64 v = arr[i];
    sitems[(size_t)b * N_PRE + i] = v;
    u32 kk = ~(u32)(v & 0xffffffffull);
    float4 bx = make_float4(0, 0, 0, 0);
    if (kk < KA) bx = roi[(size_t)b * KA + kk];
    sbox[(size_t)b * N_PRE + i] = bx;
  }
}

// ---------------- NMS suppression bitmask (upper-triangle 64x64 blocks) ----------------
__global__ __launch_bounds__(64) void k_mask(const float4* __restrict__ sbox,
    u64* __restrict__ mask, u64* __restrict__ diag) {
  const int cb = blockIdx.x, rb = blockIdx.y, b = blockIdx.z;
  if (cb < rb) return;
  const int tid = threadIdx.x;
  __shared__ float4 cbx[64];
  __shared__ float carea[64];
  int col0 = cb * 64;
  int c = col0 + tid;
  float4 v = (c < N_PRE) ? sbox[(size_t)b * N_PRE + c] : make_float4(0, 0, 0, 0);
  cbx[tid] = v;
  carea[tid] = (v.z - v.x) * (v.w - v.y);
  __syncthreads();
  int row = rb * 64 + tid;
  if (row >= N_PRE) return;
  float4 r = sbox[(size_t)b * N_PRE + row];
  float rarea = (r.z - r.x) * (r.w - r.y);
  u64 word = 0ull;
  for (int j = 0; j < 64; j++) {
    int cc = col0 + j;
    if (cc > row && cc < N_PRE) {
      float4 q = cbx[j];
      float ty = fmaxf(r.x, q.x), tx = fmaxf(r.y, q.y);
      float by = fminf(r.z, q.z), bx = fminf(r.w, q.w);
      float ihh = fmaxf(by - ty, 0.f), iww = fmaxf(bx - tx, 0.f);
      float inter = ihh * iww;
      float iou = inter / (rarea + carea[j] - inter + 1e-9f);
      if (iou > NMS_T) word |= (1ull << j);
    }
  }
  mask[((size_t)b * N_PRE + row) * NWORDS + cb] = word;
  if (cb == rb) diag[(size_t)b * N_PRE + row] = word;  // own-group suppression word
}

// ---------------- sequential NMS reduce (4-deep chained via diag) + outputs ----------------
__global__ __launch_bounds__(64) void k_nms_out(const u64* __restrict__ sitems,
    const float4* __restrict__ sbox, const u64* __restrict__ mask,
    const u64* __restrict__ diag, float* __restrict__ out) {
  const int b = blockIdx.x;
  const int lane = threadIdx.x;
  __shared__ u64 remv[NWORDS];
  __shared__ u64 pre[NWORDS];
  __shared__ u64 dia[N_PRE];
  __shared__ u32 keep[N_POST];
  for (int i = lane; i < NWORDS; i += 64) { remv[i] = 0ull; pre[i] = 0ull; }
  __syncthreads();
  u32 keyneg = ~__float_as_uint(NEGV);
  for (int i = lane; i < N_PRE; i += 64) {
    dia[i] = diag[(size_t)b * N_PRE + i];
    u32 key = (u32)(sitems[(size_t)b * N_PRE + i] >> 32);
    if (key == keyneg || key == 0u)
      atomicOr(&pre[i >> 6], 1ull << (i & 63));
  }
  if (lane == 0) pre[NWORDS - 1] |= ~((1ull << (N_PRE - 64 * (NWORDS - 1))) - 1ull);
  __syncthreads();

  int kc = 0;
  for (int g = 0; g < NWORDS && kc < N_POST; g++) {
    u64 done = 0ull;
    while (kc < N_POST) {
      u64 cur = remv[g] | pre[g] | done;
      if (cur == ~0ull) break;
      // chain up to 4 keeps using LDS-resident diag words (no global latency)
      int r0 = -1, r1 = -1, r2 = -1, r3 = -1; int m = 1;
      u64 c2 = cur;
      int bit = __ffsll((long long)(~c2)) - 1;
      r0 = g * 64 + bit; c2 |= (1ull << bit) | dia[r0]; done |= 1ull << bit;
      if (c2 != ~0ull && kc + 1 < N_POST) {
        bit = __ffsll((long long)(~c2)) - 1;
        r1 = g * 64 + bit; c2 |= (1ull << bit) | dia[r1]; done |= 1ull << bit; m = 2;
        if (c2 != ~0ull && kc + 2 < N_POST) {
          bit = __ffsll((long long)(~c2)) - 1;
          r2 = g * 64 + bit; c2 |= (1ull << bit) | dia[r2]; done |= 1ull << bit; m = 3;
          if (c2 != ~0ull && kc + 3 < N_POST) {
            bit = __ffsll((long long)(~c2)) - 1;
            r3 = g * 64 + bit; c2 |= (1ull << bit) | dia[r3]; done |= 1ull << bit; m = 4;
          }
        }
      }
      if (lane == 0) {
        keep[kc] = (u32)r0;
        if (m > 1) keep[kc + 1] = (u32)r1;
        if (m > 2) keep[kc + 2] = (u32)r2;
        if (m > 3) keep[kc + 3] = (u32)r3;
      }
      // OR the m mask rows into remv in parallel: lane j*16+l16 handles row j
      int j = lane >> 4, l16 = lane & 15;
      int rj = (j == 0) ? r0 : (j == 1) ? r1 : (j == 2) ? r2 : r3;
      if (j < m) {
        const u64* mrow = mask + ((size_t)b * N_PRE + rj) * NWORDS;
        for (int cb = g + l16; cb < NWORDS; cb += 16)
          atomicOr(&remv[cb], mrow[cb]);
      }
      kc += m;
      __syncthreads();
    }
  }
  __syncthreads();
  for (int r = lane; r < N_POST; r += 64) {
    float4 bx = make_float4(0, 0, 0, 0);
    if (r < kc) bx = sbox[(size_t)b * N_PRE + keep[r]];
    ((float4*)out)[OFF_ROIS / 4 + (size_t)b * N_POST + r] = bx;
    out[OFF_RIDX + (size_t)b * N_POST + r] = (float)b;
  }
}

// ---------------- launch ----------------
extern "C" void kernel_launch(void* const* d_in, const int* in_sizes, int n_in,
                              void* d_out, int out_size, void* d_ws, size_t ws_size,
                              hipStream_t stream) {
  const float* x   = (const float*)d_in[0];
  const float* c1w = (const float*)d_in[1];
  const float* c1b = (const float*)d_in[2];
  const float* sw  = (const float*)d_in[3];
  const float* sb  = (const float*)d_in[4];
  const float* lw  = (const float*)d_in[5];
  const float* lb  = (const float*)d_in[6];
  const int* ih    = (const int*)d_in[7];
  const int* iw    = (const int*)d_in[8];
  float* out = (float*)d_out;
  char* wsb = (char*)d_ws;

  float* hid   = (float*)(wsb + WS_HID);
  float* fg    = (float*)(wsb + WS_FG);
  float4* roi  = (float4*)(wsb + WS_ROI);
  u64* items   = (u64*)(wsb + WS_ITEMS);
  u64* sitems  = (u64*)(wsb + WS_SITEMS);
  float4* sbox = (float4*)(wsb + WS_SBOX);
  u64* maskp   = (u64*)(wsb + WS_MASK);
  u64* diagp   = (u64*)(wsb + WS_DIAG);

  hipLaunchKernelGGL(k_anchor, dim3((KA + 255) / 256), dim3(256), 0, stream, out);
  hipLaunchKernelGGL(k_conv1, dim3(8, 50, 2), dim3(64), 0, stream, x, c1w, c1b, hid);
  hipLaunchKernelGGL(k_head, dim3((N_BATCH * NPIX + 255) / 256), dim3(256), 0, stream,
                     hid, sw, sb, lw, lb, out, fg);
  hipLaunchKernelGGL(k_prep, dim3((N_BATCH * KA + 255) / 256), dim3(256), 0, stream,
                     out, fg, ih, iw, roi, items);
  hipLaunchKernelGGL(k_select, dim3(2), dim3(1024), 0, stream, items, roi, sitems, sbox);
  hipLaunchKernelGGL(k_mask, dim3(NWORDS, NWORDS, 2), dim3(64), 0, stream, sbox, maskp, diagp);
  hipLaunchKernelGGL(k_nms_out, dim3(2), dim3(64), 0, stream, sitems, sbox, maskp, diagp, out);
}

// Round 3
// 1641.072 us; speedup vs baseline: 1.5988x; 1.5988x over previous
//
#include <hip/hip_runtime.h>
#include <hip/hip_bf16.h>
#include <math.h>

// ---------------- problem constants ----------------
#define N_BATCH 2
#define HH 50
#define WW 84
#define NPIX (HH*WW)           // 4200
#define KA (NPIX*9)            // 37800
#define N_PRE 6000
#define N_POST 300
#define NMS_T 0.7f
#define NEGV (-1e9f)
#define NWORDS 94              // ceil(6000/64)

// d_out offsets (floats)
#define OFF_LOCS   0
#define OFF_SCORES (N_BATCH*KA*4)                  // 302400
#define OFF_ROIS   (OFF_SCORES + N_BATCH*KA*2)     // 453600
#define OFF_RIDX   (OFF_ROIS + N_BATCH*N_POST*4)   // 456000
#define OFF_ANCH   (OFF_RIDX + N_BATCH*N_POST)     // 456600

// ws offsets (bytes), all 16B aligned
#define WS_HID    0ull
#define WS_FG     17203200ull
#define WS_ROI    17505600ull
#define WS_ITEMS  18715200ull
#define WS_SITEMS 19320000ull
#define WS_SBOX   19416000ull
#define WS_MASK   19608000ull
#define WS_DIAG   28632000ull   // 2*6000*8 = 96000 B

typedef unsigned long long u64;
typedef unsigned u32;

// ---------------- anchors ----------------
__global__ void k_anchor(float* __restrict__ out) {
  int k = blockIdx.x * 256 + threadIdx.x;
  if (k >= KA) return;
  int a = k % 9; int pj = k / 9; int j = pj % WW; int i = pj / WW;
  int ri = a / 3, si = a % 3;
  double ratio = (ri == 0) ? 0.5 : ((ri == 1) ? 1.0 : 2.0);
  double scale = (si == 0) ? 8.0 : ((si == 1) ? 16.0 : 32.0);
  double h = 16.0 * scale * sqrt(ratio);
  double w = 16.0 * scale * sqrt(1.0 / ratio);
  float y1 = (float)(8.0 - h * 0.5), x1 = (float)(8.0 - w * 0.5);
  float y2 = (float)(8.0 + h * 0.5), x2 = (float)(8.0 + w * 0.5);
  float sy = (float)(i * 16), sx = (float)(j * 16);
  ((float4*)out)[OFF_ANCH / 4 + k] = make_float4(sy + y1, sx + x1, sy + y2, sx + x2);
}

// ---------------- conv1 3x3 512->512 + relu ----------------
// 256-thread block = 128 oc x 1 row (84 px). thread = 2 oc x 21 px (42 acc).
// grid (4,50,2) = 400 blocks = 1600 waves. Async-stage: next tile's global
// loads issued right after barrier, hidden under current tile's ~6k FMA cycles.
__global__ __launch_bounds__(256) void k_conv1(const float* __restrict__ x,
    const float* __restrict__ w, const float* __restrict__ bias,
    float* __restrict__ hid) {
  const int ocb = blockIdx.x;   // 0..3  (128 oc each)
  const int oh  = blockIdx.y;   // 0..49
  const int n   = blockIdx.z;   // 0..1
  const int tid = threadIdx.x;  // 0..255
  const int ocl = tid >> 2;     // 0..63
  const int g   = tid & 3;      // 0..3
  const int ow0 = g * 21;
  __shared__ float lx[8 * 3 * 88];   // 8448 B
  __shared__ float lw[128 * 73];     // pad 72->73, 37376 B

  const float* xg = x + (size_t)n * 512 * NPIX;
  const float* wg = w + (size_t)ocb * 128 * 4608;

  // hoisted staging addresses (advance per K-step is a uniform scalar)
  int xoff[9];
#pragma unroll
  for (int k = 0; k < 9; k++) {
    int idx = tid + k * 256;
    int ic = idx / 264; int rem = idx % 264; int ky = rem / 88; int col = rem % 88;
    int y = oh + ky - 1; int ow = col - 1;
    bool valid = (idx < 2112) && ((unsigned)y < 50u) && ((unsigned)ow < 84u);
    xoff[k] = valid ? ((ic * 50 + y) * 84 + ow) : -1;
  }
  int wbase[36];
#pragma unroll
  for (int k = 0; k < 36; k++) {
    int idx = tid + k * 256;
    wbase[k] = (idx / 72) * 4608 + (idx % 72);
  }
  int lwa[36];
#pragma unroll
  for (int k = 0; k < 36; k++) {
    int idx = tid + k * 256;
    lwa[k] = (idx / 72) * 73 + (idx % 72);
  }

  float acc0[21], acc1[21];
#pragma unroll
  for (int p = 0; p < 21; p++) { acc0[p] = 0.f; acc1[p] = 0.f; }

  float xs[9], wsv[36];
  // prologue: stage tile 0
#pragma unroll
  for (int k = 0; k < 9; k++) xs[k] = (xoff[k] >= 0) ? xg[xoff[k]] : 0.f;
#pragma unroll
  for (int k = 0; k < 36; k++) wsv[k] = wg[wbase[k]];

  for (int ic0 = 0; ic0 < 512; ic0 += 8) {
    // commit staged regs to LDS
#pragma unroll
    for (int k = 0; k < 9; k++) {
      int idx = tid + k * 256;
      if (idx < 2112) lx[idx] = xs[k];
    }
#pragma unroll
    for (int k = 0; k < 36; k++) lw[lwa[k]] = wsv[k];
    __syncthreads();

    // issue next tile's loads (latency hides under compute below)
    if (ic0 + 8 < 512) {
      int xadd = (ic0 + 8) * NPIX;
      int wadd = (ic0 + 8) * 9;
#pragma unroll
      for (int k = 0; k < 9; k++) xs[k] = (xoff[k] >= 0) ? xg[xoff[k] + xadd] : 0.f;
#pragma unroll
      for (int k = 0; k < 36; k++) wsv[k] = wg[wbase[k] + wadd];
    }

    // compute current tile
    for (int ic = 0; ic < 8; ic++) {
#pragma unroll
      for (int ky = 0; ky < 3; ky++) {
        float xv[23];
        const float* lp = &lx[(ic * 3 + ky) * 88 + ow0];
#pragma unroll
        for (int jj = 0; jj < 23; jj++) xv[jj] = lp[jj];
        const int wb = ic * 9 + ky * 3;
        const float* wp0 = &lw[(ocl * 2 + 0) * 73 + wb];
        const float* wp1 = &lw[(ocl * 2 + 1) * 73 + wb];
#pragma unroll
        for (int kx = 0; kx < 3; kx++) {
          float w0 = wp0[kx], w1 = wp1[kx];
#pragma unroll
          for (int p = 0; p < 21; p++) {
            acc0[p] = fmaf(w0, xv[p + kx], acc0[p]);
            acc1[p] = fmaf(w1, xv[p + kx], acc1[p]);
          }
        }
      }
    }
    __syncthreads();
  }

  {
    int oc = ocb * 128 + ocl * 2;
    float bv0 = bias[oc], bv1 = bias[oc + 1];
    float* op0 = &hid[((size_t)(n * 512 + oc) * 50 + oh) * 84 + ow0];
    float* op1 = op0 + (size_t)50 * 84;
#pragma unroll
    for (int p = 0; p < 21; p++) {
      float v0 = acc0[p] + bv0; op0[p] = v0 > 0.f ? v0 : 0.f;
      float v1 = acc1[p] + bv1; op1[p] = v1 > 0.f ? v1 : 0.f;
    }
  }
}

// ---------------- 1x1 heads (18 score + 36 loc) + fg softmax ----------------
__global__ __launch_bounds__(256) void k_head(const float* __restrict__ hid,
    const float* __restrict__ sw, const float* __restrict__ sb,
    const float* __restrict__ lww, const float* __restrict__ lb,
    float* __restrict__ out, float* __restrict__ fg) {
  const int tid = threadIdx.x;
  const int P0 = blockIdx.x * 256;
  const int P = P0 + tid;
  __shared__ float xt[32 * 256];
  __shared__ float wt[32 * 56];
  float acc[54];
#pragma unroll
  for (int o = 0; o < 54; o++) acc[o] = 0.f;

  for (int c0 = 0; c0 < 512; c0 += 32) {
    for (int i = tid; i < 32 * 256; i += 256) {
      int c = i >> 8; int lp = i & 255;
      int PP = P0 + lp;
      float v = 0.f;
      if (PP < N_BATCH * NPIX) {
        int n = PP / NPIX; int p = PP % NPIX;
        v = hid[(size_t)(n * 512 + c0 + c) * NPIX + p];
      }
      xt[c * 256 + lp] = v;
    }
    for (int i = tid; i < 32 * 54; i += 256) {
      int c = i / 54; int o = i % 54;
      wt[c * 56 + o] = (o < 18) ? sw[o * 512 + c0 + c] : lww[(o - 18) * 512 + c0 + c];
    }
    __syncthreads();
#pragma unroll 4
    for (int c = 0; c < 32; c++) {
      float xv = xt[c * 256 + tid];
      const float* wp = &wt[c * 56];
#pragma unroll
      for (int o = 0; o < 54; o++) acc[o] = fmaf(xv, wp[o], acc[o]);
    }
    __syncthreads();
  }

  if (P < N_BATCH * NPIX) {
    int n = P / NPIX; int p = P % NPIX;
    float raw[18];
#pragma unroll
    for (int o = 0; o < 18; o++) raw[o] = acc[o] + sb[o];
    size_t sbase = OFF_SCORES + ((size_t)n * KA + (size_t)p * 9) * 2;
#pragma unroll
    for (int o = 0; o < 18; o++) out[sbase + o] = raw[o];
    size_t lbase = OFF_LOCS + ((size_t)n * KA + (size_t)p * 9) * 4;
#pragma unroll
    for (int o = 0; o < 36; o++) out[lbase + o] = acc[18 + o] + lb[o];
#pragma unroll
    for (int a = 0; a < 9; a++) {
      float r0 = raw[2 * a], r1 = raw[2 * a + 1];
      float m = fmaxf(r0, r1);
      float e0 = expf(r0 - m), e1 = expf(r1 - m);
      fg[(size_t)n * KA + p * 9 + a] = e1 / (e0 + e1);
    }
  }
}

// ---------------- roi prep: loc2bbox + clip + size filter + sortable key ----------------
__global__ void k_prep(const float* __restrict__ out, const float* __restrict__ fg,
    const int* __restrict__ ihp, const int* __restrict__ iwp,
    float4* __restrict__ roi, u64* __restrict__ items) {
  int idx = blockIdx.x * 256 + threadIdx.x;
  if (idx >= N_BATCH * KA) return;
  int b = idx / KA; int k = idx % KA;
  float4 A = ((const float4*)out)[OFF_ANCH / 4 + k];
  float4 L = ((const float4*)out)[OFF_LOCS / 4 + (size_t)b * KA + k];
  float imh = (float)ihp[0], imw = (float)iwp[0];
  float h = A.z - A.x, w = A.w - A.y;
  float yc = A.x + 0.5f * h, xc = A.y + 0.5f * w;
  float cy = L.x * h + yc, cx = L.y * w + xc;
  float nh = expf(L.z) * h, nw = expf(L.w) * w;
  float y1 = cy - 0.5f * nh, x1 = cx - 0.5f * nw;
  float y2 = cy + 0.5f * nh, x2 = cx + 0.5f * nw;
  y1 = fminf(fmaxf(y1, 0.f), imh); y2 = fminf(fmaxf(y2, 0.f), imh);
  x1 = fminf(fmaxf(x1, 0.f), imw); x2 = fminf(fmaxf(x2, 0.f), imw);
  float hs = y2 - y1, wsz = x2 - x1;
  bool valid = (hs >= 16.f) && (wsz >= 16.f);
  float sc = valid ? fg[idx] : NEGV;
  u32 u = __float_as_uint(sc);
  u32 key = (u & 0x80000000u) ? ~u : (u | 0x80000000u);
  roi[(size_t)b * KA + k] = make_float4(y1, x1, y2, x2);
  items[(size_t)b * KA + k] = ((u64)key << 32) | (u32)(~(u32)k);
}

// ---------------- per-batch: radix-select top 6000 + bitonic sort ----------------
__global__ __launch_bounds__(1024) void k_select(const u64* __restrict__ items,
    const float4* __restrict__ roi, u64* __restrict__ sitems, float4* __restrict__ sbox) {
  const int b = blockIdx.x;
  const int tid = threadIdx.x;
  const int lane = tid & 63;
  const u64* it = items + (size_t)b * KA;
  __shared__ u64 arr[8192];
  __shared__ u32 hist[256];
  __shared__ u32 sh_need, sh_prefix, sh_cnt;
  if (tid == 0) { sh_need = N_PRE; sh_prefix = 0; sh_cnt = 0; }

  // 4-pass byte-wise radix select on high 32 bits (find kth=6000th largest key)
  for (int s = 3; s >= 0; s--) {
    for (int i = tid; i < 256; i += 1024) hist[i] = 0;
    __syncthreads();
    u32 prefix = sh_prefix;
    int t = 3 - s;
    for (int i = tid; i < KA; i += 1024) {
      u32 key = (u32)(it[i] >> 32);
      bool match = (t == 0) || ((key >> ((s + 1) * 8)) == prefix);
      if (match) atomicAdd(&hist[(key >> (s * 8)) & 255], 1u);
    }
    __syncthreads();
    if (tid == 0) {
      u32 need = sh_need; int chosen = 0;
      for (int bb = 255; bb >= 0; bb--) {
        if (need <= hist[bb]) { chosen = bb; break; }
        need -= hist[bb];
      }
      sh_need = need;
      sh_prefix = (prefix << 8) | (u32)chosen;
    }
    __syncthreads();
  }
  u32 kth = sh_prefix;

  // compact all items with key >= kth (wave-aggregated atomic)
  for (int i0 = 0; i0 < KA; i0 += 1024) {
    int i = i0 + tid;
    u64 v = (i < KA) ? it[i] : 0ull;
    bool sel = (i < KA) && ((u32)(v >> 32) >= kth);
    u64 bal = __ballot(sel);
    u32 cnt = (u32)__popcll(bal);
    u32 base = 0;
    if (lane == 0 && cnt) base = atomicAdd(&sh_cnt, cnt);
    base = (u32)__shfl((int)base, 0, 64);
    if (sel) {
      u32 pos = base + (u32)__popcll(bal & ((1ull << lane) - 1ull));
      if (pos < 8192) arr[pos] = v;
    }
  }
  __syncthreads();
  u32 T = sh_cnt; if (T > 8192) T = 8192;
  for (int i = (int)T + tid; i < 8192; i += 1024) arr[i] = 0ull;

  // bitonic sort, descending (key desc, then ~idx desc == idx asc)
  for (u32 k = 2; k <= 8192; k <<= 1) {
    for (u32 j = k >> 1; j > 0; j >>= 1) {
      __syncthreads();
      for (u32 i = tid; i < 8192; i += 1024) {
        u32 l = i ^ j;
        if (l > i) {
          u64 a = arr[i], c = arr[l];
          bool dir = ((i & k) == 0);
          if ((a < c) == dir) { arr[i] = c; arr[l] = a; }
        }
      }
    }
  }
  __syncthreads();
  for (int i = tid; i < N_PRE; i += 1024) {
    u64 v = arr[i];
    sitems[(size_t)b * N_PRE + i] = v;
    u32 kk = ~(u32)(v & 0xffffffffull);
    float4 bx = make_float4(0, 0, 0, 0);
    if (kk < KA) bx = roi[(size_t)b * KA + kk];
    sbox[(size_t)b * N_PRE + i] = bx;
  }
}

// ---------------- NMS suppression bitmask (upper-triangle 64x64 blocks) ----------------
__global__ __launch_bounds__(64) void k_mask(const float4* __restrict__ sbox,
    u64* __restrict__ mask, u64* __restrict__ diag) {
  const int cb = blockIdx.x, rb = blockIdx.y, b = blockIdx.z;
  if (cb < rb) return;
  const int tid = threadIdx.x;
  __shared__ float4 cbx[64];
  __shared__ float carea[64];
  int col0 = cb * 64;
  int c = col0 + tid;
  float4 v = (c < N_PRE) ? sbox[(size_t)b * N_PRE + c] : make_float4(0, 0, 0, 0);
  cbx[tid] = v;
  carea[tid] = (v.z - v.x) * (v.w - v.y);
  __syncthreads();
  int row = rb * 64 + tid;
  if (row >= N_PRE) return;
  float4 r = sbox[(size_t)b * N_PRE + row];
  float rarea = (r.z - r.x) * (r.w - r.y);
  u64 word = 0ull;
  for (int j = 0; j < 64; j++) {
    int cc = col0 + j;
    if (cc > row && cc < N_PRE) {
      float4 q = cbx[j];
      float ty = fmaxf(r.x, q.x), tx = fmaxf(r.y, q.y);
      float by = fminf(r.z, q.z), bx = fminf(r.w, q.w);
      float ihh = fmaxf(by - ty, 0.f), iww = fmaxf(bx - tx, 0.f);
      float inter = ihh * iww;
      float iou = inter / (rarea + carea[j] - inter + 1e-9f);
      if (iou > NMS_T) word |= (1ull << j);
    }
  }
  mask[((size_t)b * N_PRE + row) * NWORDS + cb] = word;
  if (cb == rb) diag[(size_t)b * N_PRE + row] = word;  // own-group suppression word
}

// ---------------- sequential NMS reduce (4-deep chained via diag) + outputs ----------------
__global__ __launch_bounds__(64) void k_nms_out(const u64* __restrict__ sitems,
    const float4* __restrict__ sbox, const u64* __restrict__ mask,
    const u64* __restrict__ diag, float* __restrict__ out) {
  const int b = blockIdx.x;
  const int lane = threadIdx.x;
  __shared__ u64 remv[NWORDS];
  __shared__ u64 pre[NWORDS];
  __shared__ u64 dia[N_PRE];
  __shared__ u32 keep[N_POST];
  for (int i = lane; i < NWORDS; i += 64) { remv[i] = 0ull; pre[i] = 0ull; }
  __syncthreads();
  u32 keyneg = ~__float_as_uint(NEGV);
  for (int i = lane; i < N_PRE; i += 64) {
    dia[i] = diag[(size_t)b * N_PRE + i];
    u32 key = (u32)(sitems[(size_t)b * N_PRE + i] >> 32);
    if (key == keyneg || key == 0u)
      atomicOr(&pre[i >> 6], 1ull << (i & 63));
  }
  if (lane == 0) pre[NWORDS - 1] |= ~((1ull << (N_PRE - 64 * (NWORDS - 1))) - 1ull);
  __syncthreads();

  int kc = 0;
  for (int g = 0; g < NWORDS && kc < N_POST; g++) {
    u64 done = 0ull;
    while (kc < N_POST) {
      u64 cur = remv[g] | pre[g] | done;
      if (cur == ~0ull) break;
      // chain up to 4 keeps using LDS-resident diag words (no global latency)
      int r0 = -1, r1 = -1, r2 = -1, r3 = -1; int m = 1;
      u64 c2 = cur;
      int bit = __ffsll((long long)(~c2)) - 1;
      r0 = g * 64 + bit; c2 |= (1ull << bit) | dia[r0]; done |= 1ull << bit;
      if (c2 != ~0ull && kc + 1 < N_POST) {
        bit = __ffsll((long long)(~c2)) - 1;
        r1 = g * 64 + bit; c2 |= (1ull << bit) | dia[r1]; done |= 1ull << bit; m = 2;
        if (c2 != ~0ull && kc + 2 < N_POST) {
          bit = __ffsll((long long)(~c2)) - 1;
          r2 = g * 64 + bit; c2 |= (1ull << bit) | dia[r2]; done |= 1ull << bit; m = 3;
          if (c2 != ~0ull && kc + 3 < N_POST) {
            bit = __ffsll((long long)(~c2)) - 1;
            r3 = g * 64 + bit; c2 |= (1ull << bit) | dia[r3]; done |= 1ull << bit; m = 4;
          }
        }
      }
      if (lane == 0) {
        keep[kc] = (u32)r0;
        if (m > 1) keep[kc + 1] = (u32)r1;
        if (m > 2) keep[kc + 2] = (u32)r2;
        if (m > 3) keep[kc + 3] = (u32)r3;
      }
      // OR the m mask rows into remv in parallel: lane j*16+l16 handles row j
      int j = lane >> 4, l16 = lane & 15;
      int rj = (j == 0) ? r0 : (j == 1) ? r1 : (j == 2) ? r2 : r3;
      if (j < m) {
        const u64* mrow = mask + ((size_t)b * N_PRE + rj) * NWORDS;
        for (int cb = g + l16; cb < NWORDS; cb += 16)
          atomicOr(&remv[cb], mrow[cb]);
      }
      kc += m;
      __syncthreads();
    }
  }
  __syncthreads();
  for (int r = lane; r < N_POST; r += 64) {
    float4 bx = make_float4(0, 0, 0, 0);
    if (r < kc) bx = sbox[(size_t)b * N_PRE + keep[r]];
    ((float4*)out)[OFF_ROIS / 4 + (size_t)b * N_POST + r] = bx;
    out[OFF_RIDX + (size_t)b * N_POST + r] = (float)b;
  }
}

// ---------------- launch ----------------
extern "C" void kernel_launch(void* const* d_in, const int* in_sizes, int n_in,
                              void* d_out, int out_size, void* d_ws, size_t ws_size,
                              hipStream_t stream) {
  const float* x   = (const float*)d_in[0];
  const float* c1w = (const float*)d_in[1];
  const float* c1b = (const float*)d_in[2];
  const float* sw  = (const float*)d_in[3];
  const float* sb  = (const float*)d_in[4];
  const float* lw  = (const float*)d_in[5];
  const float* lb  = (const float*)d_in[6];
  const int* ih    = (const int*)d_in[7];
  const int* iw    = (const int*)d_in[8];
  float* out = (float*)d_out;
  char* wsb = (char*)d_ws;

  float* hid   = (float*)(wsb + WS_HID);
  float* fg    = (float*)(wsb + WS_FG);
  float4* roi  = (float4*)(wsb + WS_ROI);
  u64* items   = (u64*)(wsb + WS_ITEMS);
  u64* sitems  = (u64*)(wsb + WS_SITEMS);
  float4* sbox = (float4*)(wsb + WS_SBOX);
  u64* maskp   = (u64*)(wsb + WS_MASK);
  u64* diagp   = (u64*)(wsb + WS_DIAG);

  hipLaunchKernelGGL(k_anchor, dim3((KA + 255) / 256), dim3(256), 0, stream, out);
  hipLaunchKernelGGL(k_conv1, dim3(4, 50, 2), dim3(256), 0, stream, x, c1w, c1b, hid);
  hipLaunchKernelGGL(k_head, dim3((N_BATCH * NPIX + 255) / 256), dim3(256), 0, stream,
                     hid, sw, sb, lw, lb, out, fg);
  hipLaunchKernelGGL(k_prep, dim3((N_BATCH * KA + 255) / 256), dim3(256), 0, stream,
                     out, fg, ih, iw, roi, items);
  hipLaunchKernelGGL(k_select, dim3(2), dim3(1024), 0, stream, items, roi, sitems, sbox);
  hipLaunchKernelGGL(k_mask, dim3(NWORDS, NWORDS, 2), dim3(64), 0, stream, sbox, maskp, diagp);
  hipLaunchKernelGGL(k_nms_out, dim3(2), dim3(64), 0, stream, sitems, sbox, maskp, diagp, out);
}